// Round 4
// baseline (130.049 us; speedup 1.0000x reference)
//
#include <hip/hip_runtime.h>
#include <math.h>

#define QN 32
#define SN 128
#define EN 256
#define BN 64
#define SCALE_F 20.0f
#define NB 1536     // total blocks: 1024 edq + 512 xy

// ws layout (floats): edq_part[QN*32] | xy_part[8*QN*BN] | counter (1 uint)

__device__ __forceinline__ float l1_4(float4 a, float4 b) {
    float dx = a.x - b.x, dy = a.y - b.y, dz = a.z - b.z, dw = a.w - b.w;
    return (fabsf(dx) + fabsf(dy)) + (fabsf(dz) + fabsf(dw));
}

__device__ __forceinline__ float agent_load(const float* p) {
    return __hip_atomic_load(p, __ATOMIC_RELAXED, __HIP_MEMORY_SCOPE_AGENT);
}

// Blocks [0,1024):  edq partials. q=bi&31, ic=(bi>>5)&3, jc=bi>>7.
//   Wave owns 8 i-rows (ibase=ic*32+wave*8), loops j in [jc*16, jc*16+16).
//   edq_part[q*32 + ic*8 + jc] = sum_i m_i sum_j m_j L1(a_i,a_j)
// Blocks [1024,1536): xy partials. bi2=bi-1024; q=bi2&31, bc=(bi2>>5)&1, sc=bi2>>6.
//   Wave owns 8 b-rows (bbase=bc*32+wave*8), loops s in [sc*16, sc*16+16).
//   xy_part[(sc*QN+q)*BN + b] = partial sum_s m_s L1(a_s, c_b)
// Last-arriving block (atomic counter) computes the CE loss.
__global__ __launch_bounds__(256) void kern_all(const float* __restrict__ A,
                                                const float* __restrict__ Cd,
                                                const int* __restrict__ M,
                                                float* __restrict__ edq_part,
                                                float* __restrict__ xy_part,
                                                unsigned int* __restrict__ counter,
                                                float* __restrict__ out) {
    const int bi   = blockIdx.x;
    const int wave = threadIdx.x >> 6, lane = threadIdx.x & 63;
    __shared__ float mf[SN];
    __shared__ float red[4];
    __shared__ unsigned int amLast;

    if (bi < 1024) {
        // ---------------- edq partial ----------------
        const int q = bi & 31, ic = (bi >> 5) & 3, jc = bi >> 7;
        if (threadIdx.x < SN) mf[threadIdx.x] = (float)M[q * SN + threadIdx.x];
        __syncthreads();

        const float* Aq = A + (size_t)q * SN * EN;
        const int ibase = ic * 32 + wave * 8;

        float4 ai[8];
#pragma unroll
        for (int k = 0; k < 8; ++k)
            ai[k] = *(const float4*)(Aq + (size_t)(ibase + k) * EN + lane * 4);

        float acc[8] = {0.f, 0.f, 0.f, 0.f, 0.f, 0.f, 0.f, 0.f};
        const int j0 = jc * 16;
#pragma unroll 4
        for (int j = j0; j < j0 + 16; ++j) {
            float4 aj = *(const float4*)(Aq + (size_t)j * EN + lane * 4);
            float  mj = mf[j];
#pragma unroll
            for (int k = 0; k < 8; ++k) acc[k] = fmaf(mj, l1_4(ai[k], aj), acc[k]);
        }

        float tot = 0.f;
#pragma unroll
        for (int k = 0; k < 8; ++k) tot = fmaf(mf[ibase + k], acc[k], tot);
#pragma unroll
        for (int off = 32; off; off >>= 1) tot += __shfl_down(tot, off, 64);
        if (lane == 0) red[wave] = tot;
        __syncthreads();
        if (threadIdx.x == 0)
            edq_part[q * 32 + ic * 8 + jc] = red[0] + red[1] + red[2] + red[3];
    } else {
        // ---------------- xy partial ----------------
        const int bi2 = bi - 1024;
        const int q = bi2 & 31, bc = (bi2 >> 5) & 1, sc = bi2 >> 6;
        if (threadIdx.x < SN) mf[threadIdx.x] = (float)M[q * SN + threadIdx.x];
        __syncthreads();

        const int bbase = bc * 32 + wave * 8;
        float4 cb[8];
#pragma unroll
        for (int k = 0; k < 8; ++k)
            cb[k] = *(const float4*)(Cd + (size_t)(bbase + k) * EN + lane * 4);

        float acc[8] = {0.f, 0.f, 0.f, 0.f, 0.f, 0.f, 0.f, 0.f};
        const float* Aq = A + (size_t)q * SN * EN;
        const int s0 = sc * 16;
#pragma unroll 4
        for (int s = s0; s < s0 + 16; ++s) {
            float4 as = *(const float4*)(Aq + (size_t)s * EN + lane * 4);
            float  ms = mf[s];
#pragma unroll
            for (int k = 0; k < 8; ++k) acc[k] = fmaf(ms, l1_4(as, cb[k]), acc[k]);
        }

#pragma unroll
        for (int k = 0; k < 8; ++k) {
            float t = acc[k];
#pragma unroll
            for (int off = 32; off; off >>= 1) t += __shfl_down(t, off, 64);
            if (lane == 0) xy_part[(sc * QN + q) * BN + bbase + k] = t;
        }
    }

    // ---------------- arrival; last block does the loss ----------------
    __threadfence();
    if (threadIdx.x == 0) {
        unsigned int old = atomicAdd(counter, 1u);
        amLast = (old == NB - 1) ? 1u : 0u;
    }
    __syncthreads();

    if (amLast) {
        float lsum = 0.f;
        for (int q = wave; q < QN; q += 4) {
            float mv = (float)M[q * SN + lane] + (float)M[q * SN + 64 + lane];
#pragma unroll
            for (int off = 32; off; off >>= 1) mv += __shfl_xor(mv, off, 64);
            float nv    = mv;
            float valid = fmaxf(nv, 1.f);
            float vp    = fmaxf(nv * nv, 1.f);

            float ednum = 0.f;
#pragma unroll
            for (int c = 0; c < 32; ++c) ednum += agent_load(&edq_part[q * 32 + c]);
            float edq = ednum / vp;

            float xv = 0.f;
#pragma unroll
            for (int sc = 0; sc < 8; ++sc)
                xv += agent_load(&xy_part[(sc * QN + q) * BN + lane]);

            float score = -SCALE_F * (2.f * xv / valid - edq);

            float mx = score;
#pragma unroll
            for (int off = 32; off; off >>= 1) mx = fmaxf(mx, __shfl_xor(mx, off, 64));
            float ex = expf(score - mx);
#pragma unroll
            for (int off = 32; off; off >>= 1) ex += __shfl_xor(ex, off, 64);
            float lse  = mx + logf(ex);
            float diag = __shfl(score, q, 64);
            lsum += lse - diag;
        }
        if (lane == 0) red[wave] = lsum;
        __syncthreads();
        if (threadIdx.x == 0)
            out[0] = (red[0] + red[1] + red[2] + red[3]) / (float)QN;
    }
}

extern "C" void kernel_launch(void* const* d_in, const int* in_sizes, int n_in,
                              void* d_out, int out_size, void* d_ws, size_t ws_size,
                              hipStream_t stream) {
    const float* A  = (const float*)d_in[0];   // anchors [Q,S,E] f32
    const float* Cd = (const float*)d_in[1];   // candidates [B,E] f32
    const int*   M  = (const int*)d_in[2];     // attention_mask [Q,S] i32
    float* out = (float*)d_out;

    float* edq_part = (float*)d_ws;                        // [QN*32]   = 1024 f
    float* xy_part  = edq_part + QN * 32;                  // [8*QN*BN] = 16384 f
    unsigned int* counter = (unsigned int*)(xy_part + 8 * QN * BN);

    hipMemsetAsync(counter, 0, sizeof(unsigned int), stream);
    kern_all<<<NB, 256, 0, stream>>>(A, Cd, M, edq_part, xy_part, counter, out);
}

// Round 5
// 31.796 us; speedup vs baseline: 4.0902x; 4.0902x over previous
//
#include <hip/hip_runtime.h>
#include <math.h>

#define QN 32
#define SN 128
#define EN 256
#define BN 64
#define SCALE_F 20.0f

// ws layout (floats): edq_part[QN*32] | xy_part[8*QN*BN]
// Two plain kernels; ordering via stream dependency (no fences, no atomics —
// round-4 lesson: per-block agent-scope fences cost ~100us in L2 maintenance).

__device__ __forceinline__ float l1_4(float4 a, float4 b) {
    float dx = a.x - b.x, dy = a.y - b.y, dz = a.z - b.z, dw = a.w - b.w;
    return (fabsf(dx) + fabsf(dy)) + (fabsf(dz) + fabsf(dw));
}

// Blocks [0,1024):  edq partials. q=bi&31, ic=(bi>>5)&3, jc=bi>>7.
//   Wave owns 8 i-rows (ibase=ic*32+wave*8), loops j in [jc*16, jc*16+16).
//   edq_part[q*32 + ic*8 + jc] = sum_i m_i sum_j m_j L1(a_i,a_j)
// Blocks [1024,1536): xy partials. bi2=bi-1024; q=bi2&31, bc=(bi2>>5)&1, sc=bi2>>6.
//   Wave owns 8 b-rows (bbase=bc*32+wave*8), loops s in [sc*16, sc*16+16).
//   xy_part[(sc*QN+q)*BN + b] = partial sum_s m_s L1(a_s, c_b)
__global__ __launch_bounds__(256) void kern_dist(const float* __restrict__ A,
                                                 const float* __restrict__ Cd,
                                                 const int* __restrict__ M,
                                                 float* __restrict__ edq_part,
                                                 float* __restrict__ xy_part) {
    const int bi   = blockIdx.x;
    const int wave = threadIdx.x >> 6, lane = threadIdx.x & 63;
    __shared__ float mf[SN];
    __shared__ float red[4];

    if (bi < 1024) {
        // ---------------- edq partial ----------------
        const int q = bi & 31, ic = (bi >> 5) & 3, jc = bi >> 7;
        if (threadIdx.x < SN) mf[threadIdx.x] = (float)M[q * SN + threadIdx.x];
        __syncthreads();

        const float* Aq = A + (size_t)q * SN * EN;
        const int ibase = ic * 32 + wave * 8;

        float4 ai[8];
#pragma unroll
        for (int k = 0; k < 8; ++k)
            ai[k] = *(const float4*)(Aq + (size_t)(ibase + k) * EN + lane * 4);

        float acc[8] = {0.f, 0.f, 0.f, 0.f, 0.f, 0.f, 0.f, 0.f};
        const int j0 = jc * 16;
#pragma unroll 4
        for (int j = j0; j < j0 + 16; ++j) {
            float4 aj = *(const float4*)(Aq + (size_t)j * EN + lane * 4);
            float  mj = mf[j];
#pragma unroll
            for (int k = 0; k < 8; ++k) acc[k] = fmaf(mj, l1_4(ai[k], aj), acc[k]);
        }

        float tot = 0.f;
#pragma unroll
        for (int k = 0; k < 8; ++k) tot = fmaf(mf[ibase + k], acc[k], tot);
#pragma unroll
        for (int off = 32; off; off >>= 1) tot += __shfl_down(tot, off, 64);
        if (lane == 0) red[wave] = tot;
        __syncthreads();
        if (threadIdx.x == 0)
            edq_part[q * 32 + ic * 8 + jc] = red[0] + red[1] + red[2] + red[3];
    } else {
        // ---------------- xy partial ----------------
        const int bi2 = bi - 1024;
        const int q = bi2 & 31, bc = (bi2 >> 5) & 1, sc = bi2 >> 6;
        if (threadIdx.x < SN) mf[threadIdx.x] = (float)M[q * SN + threadIdx.x];
        __syncthreads();

        const int bbase = bc * 32 + wave * 8;
        float4 cb[8];
#pragma unroll
        for (int k = 0; k < 8; ++k)
            cb[k] = *(const float4*)(Cd + (size_t)(bbase + k) * EN + lane * 4);

        float acc[8] = {0.f, 0.f, 0.f, 0.f, 0.f, 0.f, 0.f, 0.f};
        const float* Aq = A + (size_t)q * SN * EN;
        const int s0 = sc * 16;
#pragma unroll 4
        for (int s = s0; s < s0 + 16; ++s) {
            float4 as = *(const float4*)(Aq + (size_t)s * EN + lane * 4);
            float  ms = mf[s];
#pragma unroll
            for (int k = 0; k < 8; ++k) acc[k] = fmaf(ms, l1_4(as, cb[k]), acc[k]);
        }

#pragma unroll
        for (int k = 0; k < 8; ++k) {
            float t = acc[k];
#pragma unroll
            for (int off = 32; off; off >>= 1) t += __shfl_down(t, off, 64);
            if (lane == 0) xy_part[(sc * QN + q) * BN + bbase + k] = t;
        }
    }
}

// Kernel C: assemble scores, per-row logsumexp over B=64 (== wave width), mean CE loss.
__global__ __launch_bounds__(256) void kern_loss(const float* __restrict__ xy_part,
                                                 const float* __restrict__ edq_part,
                                                 const int* __restrict__ M,
                                                 float* __restrict__ out) {
    const int wave = threadIdx.x >> 6, lane = threadIdx.x & 63;
    __shared__ float red[4];
    float lsum = 0.f;
    for (int q = wave; q < QN; q += 4) {
        float mv = (float)M[q * SN + lane] + (float)M[q * SN + 64 + lane];
#pragma unroll
        for (int off = 32; off; off >>= 1) mv += __shfl_xor(mv, off, 64);
        float nv    = mv;
        float valid = fmaxf(nv, 1.f);
        float vp    = fmaxf(nv * nv, 1.f);

        float ednum = 0.f;
#pragma unroll
        for (int c = 0; c < 32; ++c) ednum += edq_part[q * 32 + c];
        float edq = ednum / vp;

        float xv = 0.f;
#pragma unroll
        for (int sc = 0; sc < 8; ++sc) xv += xy_part[(sc * QN + q) * BN + lane];

        float score = -SCALE_F * (2.f * xv / valid - edq);

        float mx = score;
#pragma unroll
        for (int off = 32; off; off >>= 1) mx = fmaxf(mx, __shfl_xor(mx, off, 64));
        float ex = __expf(score - mx);
#pragma unroll
        for (int off = 32; off; off >>= 1) ex += __shfl_xor(ex, off, 64);
        float lse  = mx + __logf(ex);
        float diag = __shfl(score, q, 64);
        lsum += lse - diag;
    }
    if (lane == 0) red[wave] = lsum;
    __syncthreads();
    if (threadIdx.x == 0)
        out[0] = (red[0] + red[1] + red[2] + red[3]) / (float)QN;
}

extern "C" void kernel_launch(void* const* d_in, const int* in_sizes, int n_in,
                              void* d_out, int out_size, void* d_ws, size_t ws_size,
                              hipStream_t stream) {
    const float* A  = (const float*)d_in[0];   // anchors [Q,S,E] f32
    const float* Cd = (const float*)d_in[1];   // candidates [B,E] f32
    const int*   M  = (const int*)d_in[2];     // attention_mask [Q,S] i32
    float* out = (float*)d_out;

    float* edq_part = (float*)d_ws;                 // [QN*32]
    float* xy_part  = edq_part + QN * 32;           // [8*QN*BN]

    kern_dist<<<1536, 256, 0, stream>>>(A, Cd, M, edq_part, xy_part);
    kern_loss<<<1, 256, 0, stream>>>(xy_part, edq_part, M, out);
}